// Round 3
// baseline (444.574 us; speedup 1.0000x reference)
//
#include <hip/hip_runtime.h>
#include <math.h>
#include <stdint.h>

// Problem shape (fixed by setup_inputs): P=512, R=256, S=256, K=3, threshold=0.
#define Pn 512
#define Rn 256
#define Sn 256

#define CHUNK 32
#define TSTRIDE 257  // odd stride -> all LDS patterns <=2-way bank alias (free)

// ---- branchless float top-3 insert (proven). Strict >, ascending visit
// order => smaller index wins ties = lax.top_k semantics. ----
__device__ __forceinline__ void ins3f(float v, int i,
    float& t0, int& i0, float& t1, int& i1, float& t2, int& i2) {
  const bool b0 = v > t0, b1 = v > t1, b2 = v > t2;
  const float nt0 = b0 ? v : t0;
  const int   ni0 = b0 ? i : i0;
  const float nt1 = b0 ? t0 : (b1 ? v : t1);
  const int   ni1 = b0 ? i0 : (b1 ? i : i1);
  const float nt2 = b1 ? t1 : (b2 ? v : t2);
  const int   ni2 = b1 ? i1 : (b2 ? i : i2);
  t0 = nt0; i0 = ni0; t1 = nt1; i1 = ni1; t2 = nt2; i2 = ni2;
}

// K1: grid = Pn*2, block = (p, row-half of 128). 4 blocks/CU (39 KB LDS),
// 16 waves/CU — 2x the occupancy of the fused version. Single full read.
//  - per-thread column top-3 over this half's 128 rows (registers)
//  - rows staged to LDS in 32-row chunks; 8 threads/row scan quarters;
//    32 threads merge -> row top-3 exp'd to global (rows complete per block).
__global__ __launch_bounds__(256, 4) void tops_kernel(
    const float* __restrict__ score,
    float* __restrict__ colpv, int* __restrict__ colpi,
    float* __restrict__ rowvg, int* __restrict__ rowig) {
  __shared__ float tile[CHUNK * TSTRIDE];   // 32,896 B
  __shared__ float pv[8 * CHUNK * 3];       //  3,072 B
  __shared__ int   pi[8 * CHUNK * 3];       //  3,072 B
  const int p  = blockIdx.x >> 1;
  const int h  = blockIdx.x & 1;
  const int s  = threadIdx.x;        // column 0..255
  const int rr = threadIdx.x & 31;   // row-in-chunk for the row scan
  const int q  = threadIdx.x >> 5;   // 8 col-quarters of 32
  const int rowbase = h * 128;
  const float* base = score + (size_t)p * (Rn * Sn) + (size_t)rowbase * Sn + s;

  float t0 = -INFINITY, t1 = -INFINITY, t2 = -INFINITY;
  int   i0 = -1, i1 = -1, i2 = -1;

  for (int c = 0; c < 4; ++c) {
    const int r0 = c * CHUNK;
    // Stage chunk (coalesced: wave reads 256B contiguous per row) + column
    // accumulate in registers. Full unroll -> 32 loads in flight.
    #pragma unroll
    for (int r = 0; r < CHUNK; ++r) {
      const float v = base[(size_t)(r0 + r) * Sn];
      tile[r * TSTRIDE + s] = v;
      ins3f(v, rowbase + r0 + r, t0, i0, t1, i1, t2, i2);
    }
    __syncthreads();
    // Row scan: thread (rr,q) scans cols q*32..q*32+31 of chunk-row rr.
    // addr = rr*257 + cb + j: banks (rr+j)%32 distinct over rr -> free.
    float k0 = -INFINITY, k1 = -INFINITY, k2 = -INFINITY;
    int   j0 = -1, j1 = -1, j2 = -1;
    const int cb = q * 32;
    #pragma unroll
    for (int j = 0; j < 32; ++j)
      ins3f(tile[rr * TSTRIDE + cb + j], cb + j, k0, j0, k1, j1, k2, j2);
    const int pb = (q * CHUNK + rr) * 3;
    pv[pb + 0] = k0; pi[pb + 0] = j0;
    pv[pb + 1] = k1; pi[pb + 1] = j1;
    pv[pb + 2] = k2; pi[pb + 2] = j2;
    __syncthreads();
    // Merge 8 quarter-partials per row (ascending q => tie semantics ok);
    // exp once, write to global. Banks (3*tid+kk)%32: gcd(3,32)=1 -> free.
    if (threadIdx.x < 32) {
      float m0 = pv[threadIdx.x * 3 + 0], m1 = pv[threadIdx.x * 3 + 1],
            m2 = pv[threadIdx.x * 3 + 2];
      int   n0 = pi[threadIdx.x * 3 + 0], n1 = pi[threadIdx.x * 3 + 1],
            n2 = pi[threadIdx.x * 3 + 2];
      #pragma unroll
      for (int qq = 1; qq < 8; ++qq) {
        const int b = (qq * CHUNK + threadIdx.x) * 3;
        #pragma unroll
        for (int kk = 0; kk < 3; ++kk)
          ins3f(pv[b + kk], pi[b + kk], m0, n0, m1, n1, m2, n2);
      }
      const size_t ro = ((size_t)p * Rn + rowbase + r0 + threadIdx.x) * 3;
      rowvg[ro + 0] = expf(m0); rowig[ro + 0] = n0;
      rowvg[ro + 1] = expf(m1); rowig[ro + 1] = n1;
      rowvg[ro + 2] = expf(m2); rowig[ro + 2] = n2;
    }
    __syncthreads();
  }
  // Half-col partials: 3 planes per half, coalesced, raw (K2 exps post-merge).
  const size_t PS = (size_t)Pn * Sn;
  const size_t o  = (size_t)p * Sn + s;
  colpv[(h * 3 + 0) * PS + o] = t0; colpi[(h * 3 + 0) * PS + o] = i0;
  colpv[(h * 3 + 1) * PS + o] = t1; colpi[(h * 3 + 1) * PS + o] = i1;
  colpv[(h * 3 + 2) * PS + o] = t2; colpi[(h * 3 + 2) * PS + o] = i2;
}

__device__ __forceinline__ void compute_elem(
    int s, int r, bool rmask, int sm,
    float rv0, float rv1, float rv2, int ri0, int ri1, int ri2,
    float a0, int b0, float a1, int b1, float a2, int b2,
    float& oscore, float& ocorr) {
  const float rv = (s == ri0) ? rv0 : (s == ri1) ? rv1 : (s == ri2) ? rv2 : 0.0f;
  const float sv = (r == b0) ? a0 : (r == b1) ? a1 : (r == b2) ? a2 : 0.0f;
  oscore = 0.5f * (rv + sv);
  const bool m = rmask && (sm != 0);
  ocorr = (((rv > 0.0f) || (sv > 0.0f)) && m) ? 1.0f : 0.0f;
}

// K2: pure streaming writer, 2048 blocks (8/CU). Merges the 2 col halves
// (ascending half order => tie semantics ok), preloads this slab's row tops
// into LDS (coalesced) and streams both output maps with float4 stores.
__global__ __launch_bounds__(256) void write_kernel(
    const float* __restrict__ colpv, const int* __restrict__ colpi,
    const float* __restrict__ rowvg, const int* __restrict__ rowig,
    const int* __restrict__ rmaskp, const int* __restrict__ smaskp,
    float* __restrict__ out) {
  __shared__ float rv[64 * 3];
  __shared__ int   ri[64 * 3];
  __shared__ int   rmk[64];
  const int p     = blockIdx.x >> 2;
  const int rbase = (blockIdx.x & 3) * 64;
  const int tid   = threadIdx.x;
  // Coalesced preload of this slab's 64 rows of top data.
  if (tid < 192) {
    const size_t rb = ((size_t)p * Rn + rbase) * 3;
    rv[tid] = rowvg[rb + tid];
    ri[tid] = rowig[rb + tid];
  }
  if (tid < 64) rmk[tid] = rmaskp[p * Rn + rbase + tid];

  const int warp  = tid >> 6;
  const int lane  = tid & 63;
  const size_t PS = (size_t)Pn * Sn;
  const size_t N  = (size_t)Pn * Rn * Sn;
  const size_t cb = (size_t)p * Sn;

  // Col tops: half-0 ranks, then insert half-1 ranks (rows 128..255 > any
  // half-0 index, strict > keeps smaller-row winner on ties).
  float4 T0 = reinterpret_cast<const float4*>(colpv + 0 * PS + cb)[lane];
  float4 T1 = reinterpret_cast<const float4*>(colpv + 1 * PS + cb)[lane];
  float4 T2 = reinterpret_cast<const float4*>(colpv + 2 * PS + cb)[lane];
  int4   I0 = reinterpret_cast<const int4*>(colpi + 0 * PS + cb)[lane];
  int4   I1 = reinterpret_cast<const int4*>(colpi + 1 * PS + cb)[lane];
  int4   I2 = reinterpret_cast<const int4*>(colpi + 2 * PS + cb)[lane];
  #pragma unroll
  for (int k = 3; k < 6; ++k) {
    const float4 V = reinterpret_cast<const float4*>(colpv + (size_t)k * PS + cb)[lane];
    const int4   J = reinterpret_cast<const int4*>(colpi + (size_t)k * PS + cb)[lane];
    ins3f(V.x, J.x, T0.x, I0.x, T1.x, I1.x, T2.x, I2.x);
    ins3f(V.y, J.y, T0.y, I0.y, T1.y, I1.y, T2.y, I2.y);
    ins3f(V.z, J.z, T0.z, I0.z, T1.z, I1.z, T2.z, I2.z);
    ins3f(V.w, J.w, T0.w, I0.w, T1.w, I1.w, T2.w, I2.w);
  }
  T0.x = expf(T0.x); T0.y = expf(T0.y); T0.z = expf(T0.z); T0.w = expf(T0.w);
  T1.x = expf(T1.x); T1.y = expf(T1.y); T1.z = expf(T1.z); T1.w = expf(T1.w);
  T2.x = expf(T2.x); T2.y = expf(T2.y); T2.z = expf(T2.z); T2.w = expf(T2.w);

  const int4 sm = reinterpret_cast<const int4*>(smaskp + cb)[lane];
  const int sbase = lane * 4;
  float* outp = out + (size_t)p * (Rn * Sn);
  __syncthreads();

  #pragma unroll 4
  for (int it = 0; it < 16; ++it) {
    const int rl = it * 4 + warp;          // row within slab
    const int r  = rbase + rl;             // global row
    const float rv0 = rv[rl * 3 + 0], rv1 = rv[rl * 3 + 1], rv2 = rv[rl * 3 + 2];
    const int   ri0 = ri[rl * 3 + 0], ri1 = ri[rl * 3 + 1], ri2 = ri[rl * 3 + 2];
    const bool  rm  = rmk[rl] != 0;

    float4 osc, oco;
    compute_elem(sbase + 0, r, rm, sm.x, rv0, rv1, rv2, ri0, ri1, ri2,
                 T0.x, I0.x, T1.x, I1.x, T2.x, I2.x, osc.x, oco.x);
    compute_elem(sbase + 1, r, rm, sm.y, rv0, rv1, rv2, ri0, ri1, ri2,
                 T0.y, I0.y, T1.y, I1.y, T2.y, I2.y, osc.y, oco.y);
    compute_elem(sbase + 2, r, rm, sm.z, rv0, rv1, rv2, ri0, ri1, ri2,
                 T0.z, I0.z, T1.z, I1.z, T2.z, I2.z, osc.z, oco.z);
    compute_elem(sbase + 3, r, rm, sm.w, rv0, rv1, rv2, ri0, ri1, ri2,
                 T0.w, I0.w, T1.w, I1.w, T2.w, I2.w, osc.w, oco.w);

    reinterpret_cast<float4*>(outp + (size_t)r * Sn)[lane]     = osc;
    reinterpret_cast<float4*>(outp + N + (size_t)r * Sn)[lane] = oco;
  }
}

extern "C" void kernel_launch(void* const* d_in, const int* in_sizes, int n_in,
                              void* d_out, int out_size, void* d_ws, size_t ws_size,
                              hipStream_t stream) {
  const float* score = (const float*)d_in[0];
  // d_in[1] = node_corr_scores: unused (conditional=False in reference)
  const int* rmask = (const int*)d_in[2];
  const int* smask = (const int*)d_in[3];
  float* out = (float*)d_out;

  const size_t PS = (size_t)Pn * Sn;
  // Workspace: 6 half-col planes (v+i) + exp'd row tops (v+i). ~9.4 MB.
  float* colpv = (float*)d_ws;                       // 6*PS floats
  int*   colpi = (int*)(colpv + 6 * PS);             // 6*PS ints
  float* rowvg = (float*)(colpi + 6 * PS);           // Pn*Rn*3 floats
  int*   rowig = (int*)(rowvg + (size_t)Pn * Rn * 3);

  tops_kernel<<<Pn * 2, 256, 0, stream>>>(score, colpv, colpi, rowvg, rowig);
  write_kernel<<<Pn * 4, 256, 0, stream>>>(colpv, colpi, rowvg, rowig,
                                           rmask, smask, out);
}

// Round 6
// 395.936 us; speedup vs baseline: 1.1228x; 1.1228x over previous
//
#include <hip/hip_runtime.h>
#include <math.h>
#include <stdint.h>

// Problem shape (fixed by setup_inputs): P=512, R=256, S=256, K=3, threshold=0.
#define Pn 512
#define Rn 256
#define Sn 256

typedef unsigned long long u64;
typedef unsigned int u32;

// ---- u64 key machinery (proven): larger key == larger value, ties broken
// toward smaller index (lax.top_k semantics). ----
__device__ __forceinline__ u32 mono(float f) {
  u32 u = __float_as_uint(f);
  return (u & 0x80000000u) ? ~u : (u | 0x80000000u);
}
__device__ __forceinline__ float unmono(u32 m) {
  u32 bits = (m & 0x80000000u) ? (m & 0x7FFFFFFFu) : ~m;
  return __uint_as_float(bits);
}
__device__ __forceinline__ u64 makekey(float v, int idx) {
  return ((u64)mono(v) << 32) | (u32)(~(u32)idx);
}
__device__ __forceinline__ int key_idx(u64 k) { return (int)(~(u32)k); }
__device__ __forceinline__ float key_val(u64 k) { return unmono((u32)(k >> 32)); }

// ---- branchless float top-3 insert (proven). Strict >, ascending visit
// order => smaller index wins ties = lax.top_k semantics. ----
__device__ __forceinline__ void ins3f(float v, int i,
    float& t0, int& i0, float& t1, int& i1, float& t2, int& i2) {
  const bool b0 = v > t0, b1 = v > t1, b2 = v > t2;
  const float nt0 = b0 ? v : t0;
  const int   ni0 = b0 ? i : i0;
  const float nt1 = b0 ? t0 : (b1 ? v : t1);
  const int   ni1 = b0 ? i0 : (b1 ? i : i1);
  const float nt2 = b1 ? t1 : (b2 ? v : t2);
  const int   ni2 = b1 ? i1 : (b2 ? i : i2);
  t0 = nt0; i0 = ni0; t1 = nt1; i1 = ni1; t2 = nt2; i2 = ni2;
}

// branchless key top-3 insert (total order on u64 keys -> EXACT tie-breaks).
__device__ __forceinline__ void ins3k(u64 k, u64& k0, u64& k1, u64& k2) {
  const bool b0 = k > k0, b1 = k > k1, b2 = k > k2;
  const u64 n0 = b0 ? k : k0;
  const u64 n1 = b0 ? k0 : (b1 ? k : k1);
  const u64 n2 = b1 ? k1 : (b2 ? k : k2);
  k0 = n0; k1 = n1; k2 = n2;
}

#define CHUNK 32
#define TSTRIDE 257  // odd stride -> all LDS patterns <=2-way bank alias (free)

// K1: R1's proven whole-p kernel (grid = Pn, passed full tripwire battery),
// with the two serial insert chains split into even/odd accumulator pairs
// (2x ILP on the critical path). Merges are done on u64 keys -> exact
// lax.top_k tie semantics preserved. No grid/LDS/sync/ws-layout change.
__global__ __launch_bounds__(256) void tops_kernel(
    const float* __restrict__ score,
    float* __restrict__ colv, int* __restrict__ coli,
    u64* __restrict__ rowk) {
  __shared__ float tile[CHUNK * TSTRIDE];   // 32,896 B
  __shared__ u64   pk[8 * CHUNK * 3];       //  6,144 B
  const int p  = blockIdx.x;
  const int s  = threadIdx.x;        // column 0..255
  const int rr = threadIdx.x & 31;   // row-in-chunk for the row scan
  const int q  = threadIdx.x >> 5;   // 8 col-quarters of 32
  const float* base = score + (size_t)p * (Rn * Sn) + s;

  // Column tops: two independent sets (even rows / odd rows).
  float ea0 = -INFINITY, ea1 = -INFINITY, ea2 = -INFINITY;
  int   ja0 = -1, ja1 = -1, ja2 = -1;
  float eb0 = -INFINITY, eb1 = -INFINITY, eb2 = -INFINITY;
  int   jb0 = -1, jb1 = -1, jb2 = -1;

  for (int c = 0; c < 8; ++c) {
    const int r0 = c * CHUNK;
    // Stage chunk (coalesced 256B/row) + column accumulate: even rows feed
    // set A, odd rows set B -> the two ins3f chains interleave (2x ILP).
    #pragma unroll 8
    for (int r = 0; r < CHUNK; r += 2) {
      const float v0 = base[(size_t)(r0 + r) * Sn];
      const float v1 = base[(size_t)(r0 + r + 1) * Sn];
      tile[r * TSTRIDE + s]       = v0;
      tile[(r + 1) * TSTRIDE + s] = v1;
      ins3f(v0, r0 + r,     ea0, ja0, ea1, ja1, ea2, ja2);
      ins3f(v1, r0 + r + 1, eb0, jb0, eb1, jb1, eb2, jb2);
    }
    __syncthreads();
    // Row scan: thread (rr,q) scans cols q*32..q*32+31 of chunk-row rr,
    // split even/odd j into two key chains, exact key-merge at the end.
    const int cb = q * 32;
    const float* trow = &tile[rr * TSTRIDE + cb];
    u64 ka0 = 0, ka1 = 0, ka2 = 0;
    u64 kb0 = 0, kb1 = 0, kb2 = 0;
    #pragma unroll 8
    for (int j = 0; j < 32; j += 2) {
      ins3k(makekey(trow[j],     cb + j),     ka0, ka1, ka2);
      ins3k(makekey(trow[j + 1], cb + j + 1), kb0, kb1, kb2);
    }
    ins3k(kb0, ka0, ka1, ka2);
    ins3k(kb1, ka0, ka1, ka2);
    ins3k(kb2, ka0, ka1, ka2);
    pk[(q * CHUNK + rr) * 3 + 0] = ka0;
    pk[(q * CHUNK + rr) * 3 + 1] = ka1;
    pk[(q * CHUNK + rr) * 3 + 2] = ka2;
    __syncthreads();
    // Merge the 8 quarter-partials per row; threads 0..31, one per row.
    if (threadIdx.x < 32) {
      u64 m0 = pk[threadIdx.x * 3 + 0];
      u64 m1 = pk[threadIdx.x * 3 + 1];
      u64 m2 = pk[threadIdx.x * 3 + 2];
      #pragma unroll
      for (int qq = 1; qq < 8; ++qq) {
        #pragma unroll
        for (int kk = 0; kk < 3; ++kk)
          ins3k(pk[(qq * CHUNK + threadIdx.x) * 3 + kk], m0, m1, m2);
      }
      const size_t ro = ((size_t)p * Rn + r0 + threadIdx.x) * 3;
      rowk[ro + 0] = m0; rowk[ro + 1] = m1; rowk[ro + 2] = m2;
    }
    __syncthreads();  // pk/tile safe to overwrite next chunk
  }

  // Exact merge of even/odd column sets via keys, then 3 complete planes.
  u64 c0 = makekey(ea0, ja0), c1 = makekey(ea1, ja1), c2 = makekey(ea2, ja2);
  ins3k(makekey(eb0, jb0), c0, c1, c2);
  ins3k(makekey(eb1, jb1), c0, c1, c2);
  ins3k(makekey(eb2, jb2), c0, c1, c2);
  const size_t PS = (size_t)Pn * Sn;
  const size_t o  = (size_t)p * Sn + s;
  colv[0 * PS + o] = key_val(c0); coli[0 * PS + o] = key_idx(c0);
  colv[1 * PS + o] = key_val(c1); coli[1 * PS + o] = key_idx(c1);
  colv[2 * PS + o] = key_val(c2); coli[2 * PS + o] = key_idx(c2);
}

__device__ __forceinline__ void compute_elem(
    int s, int r, bool rmask, int sm,
    float rv0, float rv1, float rv2, int ri0, int ri1, int ri2,
    float a0, int b0, float a1, int b1, float a2, int b2,
    float& oscore, float& ocorr) {
  const float rv = (s == ri0) ? rv0 : (s == ri1) ? rv1 : (s == ri2) ? rv2 : 0.0f;
  const float sv = (r == b0) ? a0 : (r == b1) ? a1 : (r == b2) ? a2 : 0.0f;
  oscore = 0.5f * (rv + sv);
  const bool m = rmask && (sm != 0);
  ocorr = (((rv > 0.0f) || (sv > 0.0f)) && m) ? 1.0f : 0.0f;
}

// K2: R1's proven streaming writer, verbatim (2048 blocks, 8/CU): reads only
// the tiny tops (3 complete col planes + 3 row keys/row wave-uniform),
// streams both output maps with float4 stores.
__global__ __launch_bounds__(256) void write_kernel(
    const float* __restrict__ colv, const int* __restrict__ coli,
    const u64* __restrict__ rowk,
    const int* __restrict__ rmaskp, const int* __restrict__ smaskp,
    float* __restrict__ out) {
  const int p     = blockIdx.x >> 2;
  const int rbase = (blockIdx.x & 3) * 64;
  const int warp  = threadIdx.x >> 6;
  const int lane  = threadIdx.x & 63;
  const size_t PS = (size_t)Pn * Sn;
  const size_t N  = (size_t)Pn * Rn * Sn;
  const size_t cb = (size_t)p * Sn;

  float4 T0 = reinterpret_cast<const float4*>(colv + 0 * PS + cb)[lane];
  float4 T1 = reinterpret_cast<const float4*>(colv + 1 * PS + cb)[lane];
  float4 T2 = reinterpret_cast<const float4*>(colv + 2 * PS + cb)[lane];
  int4   I0 = reinterpret_cast<const int4*>(coli + 0 * PS + cb)[lane];
  int4   I1 = reinterpret_cast<const int4*>(coli + 1 * PS + cb)[lane];
  int4   I2 = reinterpret_cast<const int4*>(coli + 2 * PS + cb)[lane];
  T0.x = expf(T0.x); T0.y = expf(T0.y); T0.z = expf(T0.z); T0.w = expf(T0.w);
  T1.x = expf(T1.x); T1.y = expf(T1.y); T1.z = expf(T1.z); T1.w = expf(T1.w);
  T2.x = expf(T2.x); T2.y = expf(T2.y); T2.z = expf(T2.z); T2.w = expf(T2.w);

  const int4 sm = reinterpret_cast<const int4*>(smaskp + cb)[lane];
  const int sbase = lane * 4;
  float* outp = out + (size_t)p * (Rn * Sn);

  #pragma unroll 4
  for (int it = 0; it < 16; ++it) {
    const int r = rbase + it * 4 + warp;
    // Row top-3: 3 wave-uniform u64 loads (L2-hot broadcast), decode + exp.
    const size_t ro = ((size_t)p * Rn + r) * 3;
    const u64 rk0 = rowk[ro + 0];
    const u64 rk1 = rowk[ro + 1];
    const u64 rk2 = rowk[ro + 2];
    const float rv0 = expf(key_val(rk0));
    const float rv1 = expf(key_val(rk1));
    const float rv2 = expf(key_val(rk2));
    const int   ri0 = key_idx(rk0), ri1 = key_idx(rk1), ri2 = key_idx(rk2);
    const bool  rm  = rmaskp[p * Rn + r] != 0;   // wave-uniform scalar load

    float4 osc, oco;
    compute_elem(sbase + 0, r, rm, sm.x, rv0, rv1, rv2, ri0, ri1, ri2,
                 T0.x, I0.x, T1.x, I1.x, T2.x, I2.x, osc.x, oco.x);
    compute_elem(sbase + 1, r, rm, sm.y, rv0, rv1, rv2, ri0, ri1, ri2,
                 T0.y, I0.y, T1.y, I1.y, T2.y, I2.y, osc.y, oco.y);
    compute_elem(sbase + 2, r, rm, sm.z, rv0, rv1, rv2, ri0, ri1, ri2,
                 T0.z, I0.z, T1.z, I1.z, T2.z, I2.z, osc.z, oco.z);
    compute_elem(sbase + 3, r, rm, sm.w, rv0, rv1, rv2, ri0, ri1, ri2,
                 T0.w, I0.w, T1.w, I1.w, T2.w, I2.w, osc.w, oco.w);

    reinterpret_cast<float4*>(outp + (size_t)r * Sn)[lane]     = osc;
    reinterpret_cast<float4*>(outp + N + (size_t)r * Sn)[lane] = oco;
  }
}

extern "C" void kernel_launch(void* const* d_in, const int* in_sizes, int n_in,
                              void* d_out, int out_size, void* d_ws, size_t ws_size,
                              hipStream_t stream) {
  const float* score = (const float*)d_in[0];
  // d_in[1] = node_corr_scores: unused (conditional=False in reference)
  const int* rmask = (const int*)d_in[2];
  const int* smask = (const int*)d_in[3];
  float* out = (float*)d_out;

  const size_t PS = (size_t)Pn * Sn;
  // Workspace: 3 complete col planes (v+i) + row top-3 u64 keys (~6.3 MB) —
  // same layout as the R1 run that passed the full tripwire battery.
  float* colv = (float*)d_ws;                      // 3*PS floats
  int*   coli = (int*)(colv + 3 * PS);             // 3*PS ints
  u64*   rowk = (u64*)(coli + 3 * PS);             // Pn*Rn*3 keys

  tops_kernel<<<Pn, 256, 0, stream>>>(score, colv, coli, rowk);
  write_kernel<<<Pn * 4, 256, 0, stream>>>(colv, coli, rowk,
                                           rmask, smask, out);
}